// Round 1
// baseline (125.665 us; speedup 1.0000x reference)
//
#include <hip/hip_runtime.h>
#include <math.h>

#define N_ATOMS 4096
#define CUTOFF  5.0f
#define TI      256              // atoms i per block (== threads)
#define NJ      16               // number of j slices
#define JT      (N_ATOMS / NJ)   // 256 atoms j per slice

__device__ __forceinline__ float pow20f(float t) {
    float t2 = t * t;
    float t4 = t2 * t2;
    float t8 = t4 * t4;
    float t16 = t8 * t8;
    return t16 * t4;
}

// grid (16,16): blockIdx.x = i-tile, blockIdx.y = j-slice. 256 threads.
__global__ __launch_bounds__(256) void eam_pair_kernel(
    const float* __restrict__ coords, const float* __restrict__ params,
    float* __restrict__ rho_part,   // [NJ][N_ATOMS]
    float* __restrict__ e_part)     // [256] one per block
{
    __shared__ float sx[JT], sy[JT], sz[JT];
    __shared__ float sre[JT], sfe[JT], sal[JT], sbe[JT];
    __shared__ float sA[JT], sB[JT], ska[JT], sla[JT];

    const int tid = threadIdx.x;
    const int bi = blockIdx.x, bj = blockIdx.y;
    const int i = bi * TI + tid;
    const int jbase = bj * JT;

    {   // stage j slice into LDS (one atom per thread)
        const int j = jbase + tid;
        sx[tid] = coords[3 * j + 0];
        sy[tid] = coords[3 * j + 1];
        sz[tid] = coords[3 * j + 2];
        const float* pj = params + 22 * j;
        sre[tid] = pj[0];
        sfe[tid] = pj[1];
        sal[tid] = pj[4];
        sbe[tid] = pj[5];
        sA[tid]  = pj[6];
        sB[tid]  = pj[7];
        ska[tid] = pj[8];
        sla[tid] = pj[9];
    }
    __syncthreads();

    const float xi = coords[3 * i + 0];
    const float yi = coords[3 * i + 1];
    const float zi = coords[3 * i + 2];
    const float* pi = params + 22 * i;
    const float re_i = pi[0], fe_i = pi[1], al_i = pi[4], be_i = pi[5];
    const float A_i = pi[6], B_i = pi[7], ka_i = pi[8], la_i = pi[9];

    float rho = 0.0f;
    float e   = 0.0f;

    #pragma unroll 4
    for (int jj = 0; jj < JT; ++jj) {
        const int j = jbase + jj;
        if (j == i) continue;
        const float dx = sx[jj] - xi;
        const float dy = sy[jj] - yi;
        const float dz = sz[jj] - zi;
        const float r2 = dx * dx + dy * dy + dz * dz;
        const float r = sqrtf(r2);

        // f_r with j's params -> contributes to rho_i (NO cutoff in reference)
        const float xj  = r / sre[jj];
        const float frj = sfe[jj] * expf(-sbe[jj] * (xj - 1.0f)) /
                          (1.0f + pow20f(xj - sla[jj]));
        rho += frj;

        if (r <= CUTOFF) {  // rare (~1% of pairs): full pair-energy term
            const float xii = r / re_i;
            const float fri = fe_i * expf(-be_i * (xii - 1.0f)) /
                              (1.0f + pow20f(xii - la_i));
            const float ph_i = A_i * expf(-al_i * (xii - 1.0f)) / (1.0f + pow20f(xii - ka_i))
                             - B_i * expf(-be_i * (xii - 1.0f)) / (1.0f + pow20f(xii - la_i));
            const float ph_j = sA[jj] * expf(-sal[jj] * (xj - 1.0f)) / (1.0f + pow20f(xj - ska[jj]))
                             - sB[jj] * expf(-sbe[jj] * (xj - 1.0f)) / (1.0f + pow20f(xj - sla[jj]));
            // ordered pairs: 0.5 (ref) * 0.5 (double count) = 0.25
            e += 0.25f * (frj / fri * ph_i + fri / frj * ph_j);
        }
    }

    rho_part[bj * N_ATOMS + i] = rho;

    // deterministic block reduction of e (4 waves of 64)
    __shared__ float red[4];
    #pragma unroll
    for (int off = 32; off > 0; off >>= 1) e += __shfl_down(e, off, 64);
    const int wid = tid >> 6;
    if ((tid & 63) == 0) red[wid] = e;
    __syncthreads();
    if (tid == 0) {
        float s = red[0] + red[1] + red[2] + red[3];
        e_part[bi * NJ + bj] = s;
    }
}

// single block, 256 threads: reduce rho partials, embedding F_i, final sum
__global__ __launch_bounds__(256) void eam_embed_kernel(
    const float* __restrict__ params,
    const float* __restrict__ rho_part,
    const float* __restrict__ e_part,
    float* __restrict__ out)
{
    const int tid = threadIdx.x;
    float acc = 0.0f;

    for (int a = 0; a < N_ATOMS / 256; ++a) {
        const int i = a * 256 + tid;
        float rho = 0.0f;
        #pragma unroll
        for (int s = 0; s < NJ; ++s) rho += rho_part[s * N_ATOMS + i];

        const float* p = params + 22 * i;
        const float rho_e = p[2], rho_s = p[3];
        const float eta = p[18], fe2 = p[19];
        const float rho_n = p[20], rho_0 = p[21];

        float F;
        if (rho < rho_n) {
            const float xn = rho / rho_n - 1.0f;
            F = p[10] + xn * (p[11] + xn * (p[12] + xn * p[13]));
        } else if (rho < rho_0) {
            const float xe = rho / rho_e - 1.0f;
            F = p[14] + xe * (p[15] + xe * (p[16] + xe * p[17]));
        } else {
            const float lt = eta * logf(rho / rho_s);
            const float t  = expf(lt);
            F = fe2 * (1.0f - lt) * t;
        }
        acc += F;
    }

    // add this thread's pair-energy partial (256 partials, one per k1 block)
    acc += e_part[tid];

    // deterministic block reduction
    __shared__ float red[4];
    #pragma unroll
    for (int off = 32; off > 0; off >>= 1) acc += __shfl_down(acc, off, 64);
    const int wid = tid >> 6;
    if ((tid & 63) == 0) red[wid] = acc;
    __syncthreads();
    if (tid == 0) out[0] = red[0] + red[1] + red[2] + red[3];
}

extern "C" void kernel_launch(void* const* d_in, const int* in_sizes, int n_in,
                              void* d_out, int out_size, void* d_ws, size_t ws_size,
                              hipStream_t stream) {
    const float* coords = (const float*)d_in[0];   // [4096][3]
    const float* params = (const float*)d_in[1];   // [4096][22]
    float* out = (float*)d_out;

    float* rho_part = (float*)d_ws;                 // NJ * N_ATOMS floats
    float* e_part   = rho_part + NJ * N_ATOMS;      // 256 floats

    dim3 grid(N_ATOMS / TI, NJ);  // (16,16)
    eam_pair_kernel<<<grid, 256, 0, stream>>>(coords, params, rho_part, e_part);
    eam_embed_kernel<<<1, 256, 0, stream>>>(params, rho_part, e_part, out);
}

// Round 2
// 35.635 us; speedup vs baseline: 3.5265x; 3.5265x over previous
//
#include <hip/hip_runtime.h>
#include <math.h>

#define N_ATOMS 4096
#define CUTOFF  5.0f
#define TI      256              // atoms i per block (== threads)
#define NJ      64               // number of j slices
#define JT      (N_ATOMS / NJ)   // 64 atoms j per slice
#define LOG2E   1.4426950408889634f

__device__ __forceinline__ float pow20f(float t) {
    float t2 = t * t;
    float t4 = t2 * t2;
    float t8 = t4 * t4;
    float t16 = t8 * t8;
    return t16 * t4;
}

// grid (16,64): blockIdx.x = i-tile (256 atoms), blockIdx.y = j-slice (64 atoms).
__global__ __launch_bounds__(256) void eam_pair_kernel(
    const float* __restrict__ coords, const float* __restrict__ params,
    float* __restrict__ rho_part,   // [NJ][N_ATOMS]
    float* __restrict__ e_part)     // [16*NJ] one per block
{
    __shared__ float sx[JT], sy[JT], sz[JT];
    __shared__ float sre_inv[JT], sfe[JT], sbe_l2e[JT], sla[JT];
    __shared__ float sA[JT], sB[JT], sal_l2e[JT], ska[JT];

    const int tid = threadIdx.x;
    const int bi = blockIdx.x, bj = blockIdx.y;
    const int i = bi * TI + tid;
    const int jbase = bj * JT;

    if (tid < JT) {   // stage j slice into LDS
        const int j = jbase + tid;
        sx[tid] = coords[3 * j + 0];
        sy[tid] = coords[3 * j + 1];
        sz[tid] = coords[3 * j + 2];
        const float* pj = params + 22 * j;
        sre_inv[tid] = __builtin_amdgcn_rcpf(pj[0]);
        sfe[tid]     = pj[1];
        sbe_l2e[tid] = pj[5] * LOG2E;
        sla[tid]     = pj[9];
        sA[tid]      = pj[6];
        sB[tid]      = pj[7];
        sal_l2e[tid] = pj[4] * LOG2E;
        ska[tid]     = pj[8];
    }
    __syncthreads();

    const float xi = coords[3 * i + 0];
    const float yi = coords[3 * i + 1];
    const float zi = coords[3 * i + 2];
    const float* pi = params + 22 * i;
    const float re_inv_i = __builtin_amdgcn_rcpf(pi[0]);
    const float fe_i = pi[1];
    const float al_l2e_i = pi[4] * LOG2E;
    const float be_l2e_i = pi[5] * LOG2E;
    const float A_i = pi[6], B_i = pi[7], ka_i = pi[8], la_i = pi[9];

    float rho = 0.0f;
    float e   = 0.0f;

    #pragma unroll 4
    for (int jj = 0; jj < JT; ++jj) {
        const int j = jbase + jj;
        if (j == i) continue;
        const float dx = sx[jj] - xi;
        const float dy = sy[jj] - yi;
        const float dz = sz[jj] - zi;
        const float r2 = dx * dx + dy * dy + dz * dz;
        const float r = __builtin_amdgcn_sqrtf(r2);

        // f_r with j's params -> contributes to rho_i (no cutoff in reference)
        const float xj  = r * sre_inv[jj];
        const float ej  = __builtin_amdgcn_exp2f(-sbe_l2e[jj] * (xj - 1.0f));
        const float dj  = __builtin_amdgcn_rcpf(1.0f + pow20f(xj - sla[jj]));
        const float frj = sfe[jj] * ej * dj;
        rho += frj;

        if (r <= CUTOFF) {  // ~1% of pairs: pair-energy term
            const float xii = r * re_inv_i;
            const float ei  = __builtin_amdgcn_exp2f(-be_l2e_i * (xii - 1.0f));
            const float di  = __builtin_amdgcn_rcpf(1.0f + pow20f(xii - la_i));
            const float fri = fe_i * ei * di;
            // phi second term shares exp & denom with f_r
            const float ph_i = A_i * __builtin_amdgcn_exp2f(-al_l2e_i * (xii - 1.0f))
                                   * __builtin_amdgcn_rcpf(1.0f + pow20f(xii - ka_i))
                             - B_i * ei * di;
            const float ph_j = sA[jj] * __builtin_amdgcn_exp2f(-sal_l2e[jj] * (xj - 1.0f))
                                      * __builtin_amdgcn_rcpf(1.0f + pow20f(xj - ska[jj]))
                             - sB[jj] * ej * dj;
            // ordered pairs: 0.5 (ref) * 0.5 (double count) = 0.25
            e += 0.25f * (frj * __builtin_amdgcn_rcpf(fri) * ph_i
                        + fri * __builtin_amdgcn_rcpf(frj) * ph_j);
        }
    }

    rho_part[bj * N_ATOMS + i] = rho;

    // deterministic block reduction of e (4 waves of 64)
    __shared__ float red[4];
    #pragma unroll
    for (int off = 32; off > 0; off >>= 1) e += __shfl_down(e, off, 64);
    const int wid = tid >> 6;
    if ((tid & 63) == 0) red[wid] = e;
    __syncthreads();
    if (tid == 0) {
        e_part[bi * NJ + bj] = red[0] + red[1] + red[2] + red[3];
    }
}

// 16 blocks x 256 threads: reduce rho partials, embedding F_i, per-block partial
__global__ __launch_bounds__(256) void eam_embed_kernel(
    const float* __restrict__ params,
    const float* __restrict__ rho_part,
    float* __restrict__ F_part)     // [16]
{
    const int tid = threadIdx.x;
    const int i = blockIdx.x * 256 + tid;

    float rho = 0.0f;
    #pragma unroll 8
    for (int s = 0; s < NJ; ++s) rho += rho_part[s * N_ATOMS + i];

    const float* p = params + 22 * i;
    float F;
    if (rho < p[20]) {
        const float xn = rho / p[20] - 1.0f;
        F = p[10] + xn * (p[11] + xn * (p[12] + xn * p[13]));
    } else if (rho < p[21]) {
        const float xe = rho / p[2] - 1.0f;
        F = p[14] + xe * (p[15] + xe * (p[16] + xe * p[17]));
    } else {
        const float lt = p[18] * logf(rho / p[3]);
        F = p[19] * (1.0f - lt) * expf(lt);
    }

    float acc = F;
    __shared__ float red[4];
    #pragma unroll
    for (int off = 32; off > 0; off >>= 1) acc += __shfl_down(acc, off, 64);
    const int wid = tid >> 6;
    if ((tid & 63) == 0) red[wid] = acc;
    __syncthreads();
    if (tid == 0) F_part[blockIdx.x] = red[0] + red[1] + red[2] + red[3];
}

// 1 block, 256 threads: final deterministic sum
__global__ __launch_bounds__(256) void eam_final_kernel(
    const float* __restrict__ e_part,   // [1024]
    const float* __restrict__ F_part,   // [16]
    float* __restrict__ out)
{
    const int tid = threadIdx.x;
    float acc = e_part[tid] + e_part[256 + tid] + e_part[512 + tid] + e_part[768 + tid];
    if (tid < 16) acc += F_part[tid];

    __shared__ float red[4];
    #pragma unroll
    for (int off = 32; off > 0; off >>= 1) acc += __shfl_down(acc, off, 64);
    const int wid = tid >> 6;
    if ((tid & 63) == 0) red[wid] = acc;
    __syncthreads();
    if (tid == 0) out[0] = red[0] + red[1] + red[2] + red[3];
}

extern "C" void kernel_launch(void* const* d_in, const int* in_sizes, int n_in,
                              void* d_out, int out_size, void* d_ws, size_t ws_size,
                              hipStream_t stream) {
    const float* coords = (const float*)d_in[0];   // [4096][3]
    const float* params = (const float*)d_in[1];   // [4096][22]
    float* out = (float*)d_out;

    float* rho_part = (float*)d_ws;                       // NJ * N_ATOMS floats
    float* e_part   = rho_part + NJ * N_ATOMS;            // 16*NJ = 1024 floats
    float* F_part   = e_part + 16 * NJ;                   // 16 floats

    dim3 grid(N_ATOMS / TI, NJ);  // (16,64)
    eam_pair_kernel<<<grid, 256, 0, stream>>>(coords, params, rho_part, e_part);
    eam_embed_kernel<<<16, 256, 0, stream>>>(params, rho_part, F_part);
    eam_final_kernel<<<1, 256, 0, stream>>>(e_part, F_part, out);
}

// Round 3
// 32.851 us; speedup vs baseline: 3.8253x; 1.0847x over previous
//
#include <hip/hip_runtime.h>
#include <math.h>

#define N_ATOMS 4096
#define CUTOFF  5.0f
#define TI      256              // atoms i per block (== threads)
#define NJ      128              // number of j slices
#define JT      (N_ATOMS / NJ)   // 32 atoms j per slice
#define LOG2E   1.4426950408889634f

__device__ __forceinline__ float pow20f(float t) {
    float t2 = t * t;
    float t4 = t2 * t2;
    float t8 = t4 * t4;
    float t16 = t8 * t8;
    return t16 * t4;
}

// LDS row layout (16 floats, 64B stride -> b128-aligned chunks):
// [0]x [1]y [2]z [3]re_inv | [4]fe [5]c0b [6]c1b [7]la | [8]c0a [9]c1a [10]ka [11]A | [12]Bof
// c0b = -be*log2e*re_inv, c1b = be*log2e  => exp arg via 1 fma
// c0a/c1a likewise for alpha; Bof = B/fe  => phi 2nd term = Bof * f_r

// grid (16,128): blockIdx.x = i-tile (256 atoms), blockIdx.y = j-slice (32 atoms).
__global__ __launch_bounds__(256) void eam_pair_kernel(
    const float* __restrict__ coords, const float* __restrict__ params,
    float* __restrict__ rho_part,   // [NJ][N_ATOMS]
    float* __restrict__ e_part)     // [16*NJ]
{
    __shared__ float spp[JT][16];

    const int tid = threadIdx.x;
    const int bi = blockIdx.x, bj = blockIdx.y;
    const int i = bi * TI + tid;
    const int jbase = bj * JT;

    if (tid < JT) {   // stage + pre-fold j slice
        const int j = jbase + tid;
        const float* pj = params + 22 * j;
        const float re_inv = __builtin_amdgcn_rcpf(pj[0]);
        const float be_l2e = pj[5] * LOG2E;
        const float al_l2e = pj[4] * LOG2E;
        spp[tid][0]  = coords[3 * j + 0];
        spp[tid][1]  = coords[3 * j + 1];
        spp[tid][2]  = coords[3 * j + 2];
        spp[tid][3]  = re_inv;
        spp[tid][4]  = pj[1];                    // fe
        spp[tid][5]  = -be_l2e * re_inv;         // c0b
        spp[tid][6]  = be_l2e;                   // c1b
        spp[tid][7]  = pj[9];                    // la
        spp[tid][8]  = -al_l2e * re_inv;         // c0a
        spp[tid][9]  = al_l2e;                   // c1a
        spp[tid][10] = pj[8];                    // ka
        spp[tid][11] = pj[6];                    // A
        spp[tid][12] = pj[7] * __builtin_amdgcn_rcpf(pj[1]);  // Bof = B/fe
    }
    __syncthreads();

    const float xi = coords[3 * i + 0];
    const float yi = coords[3 * i + 1];
    const float zi = coords[3 * i + 2];
    const float* pi = params + 22 * i;
    const float re_inv_i = __builtin_amdgcn_rcpf(pi[0]);
    const float fe_i     = pi[1];
    const float be_l2e_i = pi[5] * LOG2E;
    const float al_l2e_i = pi[4] * LOG2E;
    const float c0b_i = -be_l2e_i * re_inv_i;
    const float c0a_i = -al_l2e_i * re_inv_i;
    const float la_i = pi[9], ka_i = pi[8], A_i = pi[6];
    const float Bof_i = pi[7] * __builtin_amdgcn_rcpf(fe_i);

    float rho = 0.0f;
    float e   = 0.0f;

    #pragma unroll 4
    for (int jj = 0; jj < JT; ++jj) {
        const int j = jbase + jj;
        const float4 c0 = *(const float4*)&spp[jj][0];   // x,y,z,re_inv
        const float4 c1 = *(const float4*)&spp[jj][4];   // fe,c0b,c1b,la
        const float dx = c0.x - xi;
        const float dy = c0.y - yi;
        const float dz = c0.z - zi;
        const float r2 = fmaf(dx, dx, fmaf(dy, dy, dz * dz));
        const float r  = __builtin_amdgcn_sqrtf(r2);

        // rho path: f_r with j's params (no cutoff)
        const float ej  = __builtin_amdgcn_exp2f(fmaf(c1.y, r, c1.z));
        const float tj  = fmaf(c0.w, r, -c1.w);
        const float dj  = __builtin_amdgcn_rcpf(1.0f + pow20f(tj));
        const float frj = c1.x * ej * dj;
        rho += (j == i) ? 0.0f : frj;

        if (r <= CUTOFF && i < j) {   // pair energy, each unordered pair once
            const float4 c2 = *(const float4*)&spp[jj][8];  // c0a,c1a,ka,A
            const float Bof_j = spp[jj][12];
            // i side f_r
            const float ei  = __builtin_amdgcn_exp2f(fmaf(c0b_i, r, be_l2e_i));
            const float ti  = fmaf(re_inv_i, r, -la_i);
            const float di  = __builtin_amdgcn_rcpf(1.0f + pow20f(ti));
            const float fri = fe_i * ei * di;
            // phi terms (2nd term folded through f_r)
            const float ph_i = A_i * __builtin_amdgcn_exp2f(fmaf(c0a_i, r, al_l2e_i))
                                   * __builtin_amdgcn_rcpf(1.0f + pow20f(fmaf(re_inv_i, r, -ka_i)))
                             - Bof_i * fri;
            const float ph_j = c2.w * __builtin_amdgcn_exp2f(fmaf(c2.x, r, c2.y))
                                    * __builtin_amdgcn_rcpf(1.0f + pow20f(fmaf(c0.w, r, -c2.z)))
                             - Bof_j * frj;
            e += 0.5f * (frj * __builtin_amdgcn_rcpf(fri) * ph_i
                       + fri * __builtin_amdgcn_rcpf(frj) * ph_j);
        }
    }

    rho_part[bj * N_ATOMS + i] = rho;

    // deterministic block reduction of e (4 waves of 64)
    __shared__ float red[4];
    #pragma unroll
    for (int off = 32; off > 0; off >>= 1) e += __shfl_down(e, off, 64);
    const int wid = tid >> 6;
    if ((tid & 63) == 0) red[wid] = e;
    __syncthreads();
    if (tid == 0) {
        e_part[bi * NJ + bj] = red[0] + red[1] + red[2] + red[3];
    }
}

// 16 blocks x 256 threads: reduce rho partials, embedding F_i, per-block partial
__global__ __launch_bounds__(256) void eam_embed_kernel(
    const float* __restrict__ params,
    const float* __restrict__ rho_part,
    float* __restrict__ F_part)     // [16]
{
    const int tid = threadIdx.x;
    const int i = blockIdx.x * 256 + tid;

    float rho = 0.0f;
    #pragma unroll 8
    for (int s = 0; s < NJ; ++s) rho += rho_part[s * N_ATOMS + i];

    const float* p = params + 22 * i;
    float F;
    if (rho < p[20]) {
        const float xn = rho / p[20] - 1.0f;
        F = p[10] + xn * (p[11] + xn * (p[12] + xn * p[13]));
    } else if (rho < p[21]) {
        const float xe = rho / p[2] - 1.0f;
        F = p[14] + xe * (p[15] + xe * (p[16] + xe * p[17]));
    } else {
        const float lt = p[18] * logf(rho / p[3]);
        F = p[19] * (1.0f - lt) * expf(lt);
    }

    float acc = F;
    __shared__ float red[4];
    #pragma unroll
    for (int off = 32; off > 0; off >>= 1) acc += __shfl_down(acc, off, 64);
    const int wid = tid >> 6;
    if ((tid & 63) == 0) red[wid] = acc;
    __syncthreads();
    if (tid == 0) F_part[blockIdx.x] = red[0] + red[1] + red[2] + red[3];
}

// 1 block, 256 threads: final deterministic sum
__global__ __launch_bounds__(256) void eam_final_kernel(
    const float* __restrict__ e_part,   // [2048]
    const float* __restrict__ F_part,   // [16]
    float* __restrict__ out)
{
    const int tid = threadIdx.x;
    float acc = 0.0f;
    #pragma unroll
    for (int k = 0; k < 16 * NJ / 256; ++k) acc += e_part[k * 256 + tid];
    if (tid < 16) acc += F_part[tid];

    __shared__ float red[4];
    #pragma unroll
    for (int off = 32; off > 0; off >>= 1) acc += __shfl_down(acc, off, 64);
    const int wid = tid >> 6;
    if ((tid & 63) == 0) red[wid] = acc;
    __syncthreads();
    if (tid == 0) out[0] = red[0] + red[1] + red[2] + red[3];
}

extern "C" void kernel_launch(void* const* d_in, const int* in_sizes, int n_in,
                              void* d_out, int out_size, void* d_ws, size_t ws_size,
                              hipStream_t stream) {
    const float* coords = (const float*)d_in[0];   // [4096][3]
    const float* params = (const float*)d_in[1];   // [4096][22]
    float* out = (float*)d_out;

    float* rho_part = (float*)d_ws;                       // NJ * N_ATOMS floats
    float* e_part   = rho_part + NJ * N_ATOMS;            // 16*NJ floats
    float* F_part   = e_part + 16 * NJ;                   // 16 floats

    dim3 grid(N_ATOMS / TI, NJ);  // (16,128)
    eam_pair_kernel<<<grid, 256, 0, stream>>>(coords, params, rho_part, e_part);
    eam_embed_kernel<<<16, 256, 0, stream>>>(params, rho_part, F_part);
    eam_final_kernel<<<1, 256, 0, stream>>>(e_part, F_part, out);
}